// Round 7
// baseline (246.150 us; speedup 1.0000x reference)
//
#include <hip/hip_runtime.h>

// ---------- common helpers ----------
typedef __attribute__((ext_vector_type(8))) unsigned short ushort8v;
typedef __attribute__((ext_vector_type(8))) __bf16 bf16x8;
typedef __attribute__((ext_vector_type(4))) float floatx4;

__device__ __forceinline__ unsigned short f2b(float f) {
    unsigned u = __float_as_uint(f);
    unsigned r = u + 0x7fffu + ((u >> 16) & 1u);   // RNE
    return (unsigned short)(r >> 16);
}
__device__ __forceinline__ float b2f(unsigned short h) {
    return __uint_as_float(((unsigned)h) << 16);
}

// ============================================================================
// Fragment-swizzled layout: tensor [T16][KC][16][8] bf16;
//   elem (t16, kc, l, e) = Mat[t16*16 + l][kc*8 + e]
// MFMA 16x16x32 fragment at kc0: lane(quad,l16) reads 16B at
//   ((t16*KC + kc0 + quad)*16 + l16)*16 B -> 64 lanes = 1KB contiguous.
// R6 post-mortem: 1 wave/SIMD (occ 9.4%) -> all latency exposed; MfmaUtil
// pinned 22% across 5 structures. R7 = the untested quadrant: free-running
// fragment-direct loads + 2 waves/SIMD (64x64 wave tile, 64-thr blocks,
// 2048 blocks = 8/CU).
// ============================================================================

// ---------- fused prep ----------
// blocks [0,2048):      x (8192x2048 f32) -> A2x swizzled bf16 (KC=256), 4 blocks/slab
// blocks [2048,4096):   W (2048x1023 f32) -> B2w swizzled bf16 (KC=256)
// blocks [4096,5120):   softmax(leaf_dist) -> B2p swizzled bf16 (KC=128), c>=1000 zero
__global__ __launch_bounds__(256) void prep_kernel(const float* __restrict__ x,
                                                   unsigned short* __restrict__ A2x,
                                                   const float* __restrict__ W,
                                                   unsigned short* __restrict__ B2w,
                                                   const float* __restrict__ ld_,
                                                   unsigned short* __restrict__ B2p) {
    __shared__ float tile[32 * 33];
    __shared__ float buf[1000];
    __shared__ float red[8];
    const int b = blockIdx.x, t = threadIdx.x;
    if (b < 2048) {                        // ---- cvt+swizzle x: quarter of a 16-row slab ----
        const int mt = b >> 2, kq = (b & 3) * 64;
        const int kco = t >> 4, l16 = t & 15;       // kco 0..15
        const float* xr0 = x + (size_t)(mt * 16 + l16) * 2048;
#pragma unroll
        for (int i = 0; i < 4; i++) {
            const int kc = kq + i * 16 + kco;
            const float* xr = xr0 + kc * 8;
            float4 v0 = *(const float4*)xr;
            float4 v1 = *(const float4*)(xr + 4);
            ushort8v o;
            o[0] = f2b(v0.x); o[1] = f2b(v0.y); o[2] = f2b(v0.z); o[3] = f2b(v0.w);
            o[4] = f2b(v1.x); o[5] = f2b(v1.y); o[6] = f2b(v1.z); o[7] = f2b(v1.w);
            *(ushort8v*)(A2x + ((size_t)(mt * 256 + kc) * 16 + l16) * 8) = o;
        }
    } else if (b < 4096) {                 // ---- transpose+swizzle W ----
        const int idx = b - 2048;
        const int n0 = (idx & 31) * 32, k0 = (idx >> 5) * 32;
        const int tx = t & 31, ty = t >> 5;
#pragma unroll
        for (int i = 0; i < 4; i++) {
            int k = k0 + ty + i * 8, n = n0 + tx;
            tile[(ty + i * 8) * 33 + tx] = (n < 1023) ? W[(size_t)k * 1023 + n] : 0.f;
        }
        __syncthreads();
#pragma unroll
        for (int i = 0; i < 4; i++) {
            int n = n0 + ty + i * 8, k = k0 + tx;
            size_t off = ((size_t)((n >> 4) * 256 + (k >> 3)) * 16 + (n & 15)) * 8 + (k & 7);
            B2w[off] = f2b(tile[tx * 33 + ty + i * 8]);
        }
    } else {                               // ---- softmax -> B2p swizzled (+zero pad) ----
        const int l0 = b - 4096;
        const float* r = ld_ + (size_t)l0 * 1000;
        float mx = -3.4e38f;
        for (int i = t; i < 1000; i += 256) { float v = r[i]; buf[i] = v; mx = fmaxf(mx, v); }
#pragma unroll
        for (int o = 32; o > 0; o >>= 1) mx = fmaxf(mx, __shfl_down(mx, o));
        if ((t & 63) == 0) red[t >> 6] = mx;
        __syncthreads();
        mx = fmaxf(fmaxf(red[0], red[1]), fmaxf(red[2], red[3]));
        float s = 0.f;
        for (int i = t; i < 1000; i += 256) { float e = __expf(buf[i] - mx); buf[i] = e; s += e; }
#pragma unroll
        for (int o = 32; o > 0; o >>= 1) s += __shfl_down(s, o);
        if ((t & 63) == 0) red[4 + (t >> 6)] = s;
        __syncthreads();
        float inv = 1.f / (red[4] + red[5] + red[6] + red[7]);
        for (int i = t; i < 1024; i += 256) {
            float pv = (i < 1000) ? buf[i] * inv : 0.f;
            size_t off = ((size_t)((i >> 4) * 128 + (l0 >> 3)) * 16 + (i & 15)) * 8 + (l0 & 7);
            B2p[off] = f2b(pv);
        }
    }
}

// ---------- pp: literal reference recurrence; reads dec row-major, writes A2p swizzled ----------
__global__ __launch_bounds__(256) void pp_kernel(const unsigned short* __restrict__ dec,
                                                 unsigned short* __restrict__ A2p) {
    __shared__ float d[1024];
    __shared__ float pa[1024], pb[1024];
    const int t = threadIdx.x;
    const int rrow = blockIdx.x;
    const unsigned short* row = dec + (size_t)rrow * 1024;
    for (int i = t; i < 1024; i += 256) d[i] = (i < 1023) ? b2f(row[i]) : 0.f;
    if (t == 0) pa[0] = 1.f;
    __syncthreads();
    float* cur = pa; float* nxt = pb;
    for (int dep = 0; dep < 10; dep++) {
        const int half = 1 << dep;
        const int len = half << 1;
        for (int j = t; j < len; j += 256) {
            int tt = j >> dep;
            int s  = j & (half - 1);
            int i2 = 2 * s + tt;
            int u  = i2 >> dep;
            int rr = i2 & (half - 1);
            float dv = d[half - 1 + rr];
            nxt[j] = cur[rr] * (u ? (1.f - dv) : dv);
        }
        __syncthreads();
        float* tmp = cur; cur = nxt; nxt = tmp;
    }
    const int mtb = (rrow >> 4) * 128;     // KC=128 for A2p
    const int li  = (rrow & 15) * 8;
    for (int i = t; i < 1024; i += 256) {
        size_t off = ((size_t)(mtb + (i >> 3)) * 16) * 8 + li + (i & 7);
        A2p[off] = f2b(cur[i]);
    }
}

// ---------- LDS-free fragment-direct bf16 GEMM, wave tile 64x64, 2 waves/SIMD ----------
// Block = ONE wave (64 thr). Grid 2048 = 128 bm x 16 bn tiles = 8 blocks/CU
// = 2 waves/SIMD: TLP covers VMEM latency that R6's single wave exposed.
// Per iter (BK=32): 4 A-frag + 4 B-frag 1KB loads -> 16 MFMA.
// acc 64 AGPR; launch_bounds(64,2) caps wave at 256 regs -> 2 resident.
// XCD swizzle: xcd g owns bm-tiles [16g,16g+16) for all 16 bn.
// EPI 0: sigmoid(acc+bias[col]) -> bf16 ld=1024. EPI 1: f32, col<1000.
template <int EPI>
__global__ __launch_bounds__(64, 2) void gemm_frag(const unsigned short* __restrict__ A2,
                                                   const unsigned short* __restrict__ B2,
                                                   const float* __restrict__ bias,
                                                   unsigned short* __restrict__ obf,
                                                   float* __restrict__ of32,
                                                   int KC, int ldo) {
    const int lane = threadIdx.x & 63;
    const int quad = lane >> 4, l16 = lane & 15;

    const int l   = blockIdx.x;
    const int xcd = l & 7;
    const int j   = l >> 3;                    // 0..255
    const int bm  = xcd * 16 + (j & 15);       // 64-row tile idx 0..127
    const int bn  = j >> 4;                    // 64-col tile idx 0..15

    const int mt0 = bm * 4;                    // 4 consecutive 16-row slabs
    const int nt0 = bn * 4;                    // 4 consecutive 16-col slabs

    const int lofs = (quad * 16 + l16) * 8;    // fragment lane offset (elements)
    const unsigned short* ap[4];
    const unsigned short* bp[4];
#pragma unroll
    for (int mi = 0; mi < 4; mi++) ap[mi] = A2 + (size_t)(mt0 + mi) * KC * 128 + lofs;
#pragma unroll
    for (int ni = 0; ni < 4; ni++) bp[ni] = B2 + (size_t)(nt0 + ni) * KC * 128 + lofs;

    floatx4 acc[4][4] = {};
    const int NIT = KC >> 2;                   // BK=32 -> 4 kchunks/iter

#pragma unroll 2
    for (int it = 0; it < NIT; it++) {
        const size_t ko = (size_t)it * 512;    // 4 kchunks * 128 elems
        bf16x8 af[4], bfv[4];
#pragma unroll
        for (int mi = 0; mi < 4; mi++)
            af[mi] = __builtin_bit_cast(bf16x8, *(const ushort8v*)(ap[mi] + ko));
#pragma unroll
        for (int ni = 0; ni < 4; ni++)
            bfv[ni] = __builtin_bit_cast(bf16x8, *(const ushort8v*)(bp[ni] + ko));
#pragma unroll
        for (int mi = 0; mi < 4; mi++)
#pragma unroll
            for (int ni = 0; ni < 4; ni++)
                acc[mi][ni] = __builtin_amdgcn_mfma_f32_16x16x32_bf16(
                    af[mi], bfv[ni], acc[mi][ni], 0, 0, 0);
    }

#pragma unroll
    for (int ni = 0; ni < 4; ni++) {
        const int col = (nt0 + ni) * 16 + l16;
        float bb = 0.f;
        if constexpr (EPI == 0) bb = (col < 1023) ? bias[col] : 0.f;
#pragma unroll
        for (int mi = 0; mi < 4; mi++) {
            const int row0 = (mt0 + mi) * 16 + quad * 4;
#pragma unroll
            for (int r = 0; r < 4; r++) {
                float v = acc[mi][ni][r];
                if constexpr (EPI == 0) {
                    float sgm = 1.f / (1.f + __expf(-(v + bb)));
                    obf[(size_t)(row0 + r) * ldo + col] = f2b(sgm);
                } else {
                    if (col < 1000) of32[(size_t)(row0 + r) * ldo + col] = v;
                }
            }
        }
    }
}

// ---------- host ----------
extern "C" void kernel_launch(void* const* d_in, const int* in_sizes, int n_in,
                              void* d_out, int out_size, void* d_ws, size_t ws_size,
                              hipStream_t stream) {
    const float* x   = (const float*)d_in[0];   // 8192x2048
    const float* W   = (const float*)d_in[1];   // 2048x1023
    const float* b   = (const float*)d_in[2];   // 1023
    const float* ldd = (const float*)d_in[3];   // 1024x1000
    float* out = (float*)d_out;                 // 8192x1000

    char* ws = (char*)d_ws;
    unsigned short* A2x = (unsigned short*)(ws);              // 33,554,432 B (swizzled x bf16)
    unsigned short* A2p = (unsigned short*)(ws);              // overlay: pp output (A2x dead by then)
    unsigned short* B2w = (unsigned short*)(ws + 33554432);   // 4,194,304 B (swizzled W^T)
    unsigned short* dec = (unsigned short*)(ws + 37748736);   // 16,777,216 B (row-major decisions)
    unsigned short* B2p = (unsigned short*)(ws + 54525952);   // 2,097,152 B (swizzled P^T)

    // prep: x-swizzle | W-transpose-swizzle | softmax->swizzle (independent)
    prep_kernel<<<5120, 256, 0, stream>>>(x, A2x, W, B2w, ldd, B2p);
    // decisions = sigmoid(x@W + b), row-major bf16 (cols padded to 1024)
    gemm_frag<0><<<2048, 64, 0, stream>>>(A2x, B2w, b, dec, nullptr, 256, 1024);
    // pp (reference-literal order), writes swizzled A2p
    pp_kernel<<<8192, 256, 0, stream>>>(dec, A2p);
    // out = pp @ P
    gemm_frag<1><<<2048, 64, 0, stream>>>(A2p, B2p, nullptr, nullptr, out, 128, 1000);
}

// Round 8
// 214.327 us; speedup vs baseline: 1.1485x; 1.1485x over previous
//
#include <hip/hip_runtime.h>

// ---------- common helpers ----------
typedef __attribute__((ext_vector_type(8))) unsigned short ushort8v;
typedef __attribute__((ext_vector_type(8))) __bf16 bf16x8;
typedef __attribute__((ext_vector_type(4))) float floatx4;

__device__ __forceinline__ unsigned short f2b(float f) {
    unsigned u = __float_as_uint(f);
    unsigned r = u + 0x7fffu + ((u >> 16) & 1u);   // RNE
    return (unsigned short)(r >> 16);
}
__device__ __forceinline__ float b2f(unsigned short h) {
    return __uint_as_float(((unsigned)h) << 16);
}

// ============================================================================
// Fragment-swizzled layout: tensor [T16][KC][16][8] bf16;
//   elem (t16, kc, l, e) = Mat[t16*16 + l][kc*8 + e]
// MFMA 16x16x32 fragment at kc0: lane(quad,l16) reads 16B at
//   ((t16*KC + kc0 + quad)*16 + l16)*16 B -> 64 lanes = 1KB contiguous.
// R7 post-mortem: gemm time invariant to K (gemm1==gemm2 all rounds) ->
// K-loop is latency-serialized per iteration (only one iter of fragment
// regs fits at 144 VGPR). R8: explicit even/odd register double-buffer,
// loads for it+1 issued before MFMAs of it; launch_bounds(128,2) = 256-reg
// budget (96 frag + 128 acc + addr).
// ============================================================================

// ---------- fused prep ----------
// blocks [0,2048):      x (8192x2048 f32) -> A2x swizzled bf16 (KC=256)
// blocks [2048,4096):   W (2048x1023 f32) -> B2w swizzled bf16 (KC=256)
// blocks [4096,5120):   softmax(leaf_dist) -> B2p swizzled bf16 (KC=128), c>=1000 zero
__global__ __launch_bounds__(256) void prep_kernel(const float* __restrict__ x,
                                                   unsigned short* __restrict__ A2x,
                                                   const float* __restrict__ W,
                                                   unsigned short* __restrict__ B2w,
                                                   const float* __restrict__ ld_,
                                                   unsigned short* __restrict__ B2p) {
    __shared__ float tile[32 * 33];
    __shared__ float buf[1000];
    __shared__ float red[8];
    const int b = blockIdx.x, t = threadIdx.x;
    if (b < 2048) {                        // ---- cvt+swizzle x: quarter of a 16-row slab ----
        const int mt = b >> 2, kq = (b & 3) * 64;
        const int kco = t >> 4, l16 = t & 15;       // kco 0..15
        const float* xr0 = x + (size_t)(mt * 16 + l16) * 2048;
#pragma unroll
        for (int i = 0; i < 4; i++) {
            const int kc = kq + i * 16 + kco;
            const float* xr = xr0 + kc * 8;
            float4 v0 = *(const float4*)xr;
            float4 v1 = *(const float4*)(xr + 4);
            ushort8v o;
            o[0] = f2b(v0.x); o[1] = f2b(v0.y); o[2] = f2b(v0.z); o[3] = f2b(v0.w);
            o[4] = f2b(v1.x); o[5] = f2b(v1.y); o[6] = f2b(v1.z); o[7] = f2b(v1.w);
            *(ushort8v*)(A2x + ((size_t)(mt * 256 + kc) * 16 + l16) * 8) = o;
        }
    } else if (b < 4096) {                 // ---- transpose+swizzle W ----
        const int idx = b - 2048;
        const int n0 = (idx & 31) * 32, k0 = (idx >> 5) * 32;
        const int tx = t & 31, ty = t >> 5;
#pragma unroll
        for (int i = 0; i < 4; i++) {
            int k = k0 + ty + i * 8, n = n0 + tx;
            tile[(ty + i * 8) * 33 + tx] = (n < 1023) ? W[(size_t)k * 1023 + n] : 0.f;
        }
        __syncthreads();
#pragma unroll
        for (int i = 0; i < 4; i++) {
            int n = n0 + ty + i * 8, k = k0 + tx;
            size_t off = ((size_t)((n >> 4) * 256 + (k >> 3)) * 16 + (n & 15)) * 8 + (k & 7);
            B2w[off] = f2b(tile[tx * 33 + ty + i * 8]);
        }
    } else {                               // ---- softmax -> B2p swizzled (+zero pad) ----
        const int l0 = b - 4096;
        const float* r = ld_ + (size_t)l0 * 1000;
        float mx = -3.4e38f;
        for (int i = t; i < 1000; i += 256) { float v = r[i]; buf[i] = v; mx = fmaxf(mx, v); }
#pragma unroll
        for (int o = 32; o > 0; o >>= 1) mx = fmaxf(mx, __shfl_down(mx, o));
        if ((t & 63) == 0) red[t >> 6] = mx;
        __syncthreads();
        mx = fmaxf(fmaxf(red[0], red[1]), fmaxf(red[2], red[3]));
        float s = 0.f;
        for (int i = t; i < 1000; i += 256) { float e = __expf(buf[i] - mx); buf[i] = e; s += e; }
#pragma unroll
        for (int o = 32; o > 0; o >>= 1) s += __shfl_down(s, o);
        if ((t & 63) == 0) red[4 + (t >> 6)] = s;
        __syncthreads();
        float inv = 1.f / (red[4] + red[5] + red[6] + red[7]);
        for (int i = t; i < 1024; i += 256) {
            float pv = (i < 1000) ? buf[i] * inv : 0.f;
            size_t off = ((size_t)((i >> 4) * 128 + (l0 >> 3)) * 16 + (i & 15)) * 8 + (l0 & 7);
            B2p[off] = f2b(pv);
        }
    }
}

// ---------- pp: 8 rows per block (barriers amortized), writes A2p swizzled ----------
// LDS: d 8x1024 bf16 (16KB) + pa/pb 8x1024 f32 (64KB) = 80KB -> 2 blocks/CU.
__global__ __launch_bounds__(256) void pp_kernel(const unsigned short* __restrict__ dec,
                                                 unsigned short* __restrict__ A2p) {
    __shared__ unsigned short dsh[8 * 1024];
    __shared__ float pa[8 * 1024];
    __shared__ float pb[8 * 1024];
    const int t = threadIdx.x;
    const int r0 = blockIdx.x * 8;
    // load 8 rows of dec (16KB contiguous) as ushort8
    {
        const ushort8v* src = (const ushort8v*)(dec + (size_t)r0 * 1024);
        ushort8v* dst = (ushort8v*)dsh;
        for (int g = t; g < 1024; g += 256) dst[g] = src[g];
    }
    if (t < 8) pa[t * 1024] = 1.f;
    __syncthreads();
    float* cur = pa; float* nxt = pb;
    for (int dep = 0; dep < 10; dep++) {
        const int half = 1 << dep;
        const int len  = half << 1;
        const int total = len << 3;        // 8 rows
        for (int idx = t; idx < total; idx += 256) {
            const int r = idx >> (dep + 1);
            const int j = idx & (len - 1);
            int tt = j >> dep;
            int s  = j & (half - 1);
            int i2 = 2 * s + tt;
            int u  = i2 >> dep;
            int rr = i2 & (half - 1);
            float dv = b2f(dsh[r * 1024 + half - 1 + rr]);
            nxt[r * 1024 + j] = cur[r * 1024 + rr] * (u ? (1.f - dv) : dv);
        }
        __syncthreads();
        float* tmp = cur; cur = nxt; nxt = tmp;
    }
    // write swizzled A2p (KC=128): off(row, j)
    for (int i = t; i < 8192; i += 256) {
        const int r = i >> 10, j = i & 1023;
        const int rrow = r0 + r;
        size_t off = ((size_t)((rrow >> 4) * 128 + (j >> 3)) * 16 + (rrow & 15)) * 8 + (j & 7);
        A2p[off] = f2b(cur[r * 1024 + j]);
    }
}

// ---------- LDS-free fragment-direct bf16 GEMM, wave tile 64x128 ----------
// Explicit even/odd register double-buffer: loads for iter i+1 are issued
// BEFORE the MFMAs of iter i, so each iteration's vmcnt wait covers data
// issued one full iteration earlier. launch_bounds(128,2) -> 256-reg cap.
// Block = 128 thr = 2 waves (row halves) -> block tile 128x128; grid 512.
// XCD swizzle: xcd g owns bm-tiles [8g,8g+8) for all 8 bn.
// EPI 0: sigmoid(acc+bias[col]) -> bf16 ld=1024. EPI 1: f32, col<1000.
template <int EPI>
__global__ __launch_bounds__(128, 2) void gemm_frag(const unsigned short* __restrict__ A2,
                                                    const unsigned short* __restrict__ B2,
                                                    const float* __restrict__ bias,
                                                    unsigned short* __restrict__ obf,
                                                    float* __restrict__ of32,
                                                    int KC, int ldo) {
    const int tid  = threadIdx.x;
    const int lane = tid & 63;
    const int wave = tid >> 6;                 // 0,1 = row halves
    const int quad = lane >> 4, l16 = lane & 15;

    const int l   = blockIdx.x;
    const int xcd = l & 7;
    const int j   = l >> 3;                    // 0..63
    const int bm  = xcd * 8 + (j & 7);         // 128-row tile idx 0..63
    const int bn  = j >> 3;                    // 128-col tile idx 0..7

    const int mt0 = bm * 8 + wave * 4;         // 4 consecutive 16-row slabs
    const int nt0 = bn * 8;                    // 8 consecutive 16-col slabs

    const int lofs = (quad * 16 + l16) * 8;    // fragment lane offset (elements)
    const unsigned short* ap[4];
    const unsigned short* bp[8];
#pragma unroll
    for (int mi = 0; mi < 4; mi++) ap[mi] = A2 + (size_t)(mt0 + mi) * KC * 128 + lofs;
#pragma unroll
    for (int ni = 0; ni < 8; ni++) bp[ni] = B2 + (size_t)(nt0 + ni) * KC * 128 + lofs;

    floatx4 acc[4][8] = {};
    const int NIT = KC >> 2;                   // BK=32 -> 4 kchunks/iter (NIT even)

    bf16x8 a0[4], b0[8], a1[4], b1[8];
    // prologue: load iter 0 into set0
#pragma unroll
    for (int mi = 0; mi < 4; mi++)
        a0[mi] = __builtin_bit_cast(bf16x8, *(const ushort8v*)(ap[mi]));
#pragma unroll
    for (int ni = 0; ni < 8; ni++)
        b0[ni] = __builtin_bit_cast(bf16x8, *(const ushort8v*)(bp[ni]));

    for (int it = 0; it < NIT; it += 2) {
        // issue loads for it+1 into set1 (always valid: it+1 <= NIT-1)
        {
            const size_t ko = (size_t)(it + 1) * 512;
#pragma unroll
            for (int mi = 0; mi < 4; mi++)
                a1[mi] = __builtin_bit_cast(bf16x8, *(const ushort8v*)(ap[mi] + ko));
#pragma unroll
            for (int ni = 0; ni < 8; ni++)
                b1[ni] = __builtin_bit_cast(bf16x8, *(const ushort8v*)(bp[ni] + ko));
        }
        // MFMA on set0 (data requested one iteration ago)
#pragma unroll
        for (int mi = 0; mi < 4; mi++)
#pragma unroll
            for (int ni = 0; ni < 8; ni++)
                acc[mi][ni] = __builtin_amdgcn_mfma_f32_16x16x32_bf16(
                    a0[mi], b0[ni], acc[mi][ni], 0, 0, 0);
        // issue loads for it+2 into set0
        if (it + 2 < NIT) {
            const size_t ko = (size_t)(it + 2) * 512;
#pragma unroll
            for (int mi = 0; mi < 4; mi++)
                a0[mi] = __builtin_bit_cast(bf16x8, *(const ushort8v*)(ap[mi] + ko));
#pragma unroll
            for (int ni = 0; ni < 8; ni++)
                b0[ni] = __builtin_bit_cast(bf16x8, *(const ushort8v*)(bp[ni] + ko));
        }
        // MFMA on set1
#pragma unroll
        for (int mi = 0; mi < 4; mi++)
#pragma unroll
            for (int ni = 0; ni < 8; ni++)
                acc[mi][ni] = __builtin_amdgcn_mfma_f32_16x16x32_bf16(
                    a1[mi], b1[ni], acc[mi][ni], 0, 0, 0);
    }

#pragma unroll
    for (int ni = 0; ni < 8; ni++) {
        const int col = (nt0 + ni) * 16 + l16;
        float bb = 0.f;
        if constexpr (EPI == 0) bb = (col < 1023) ? bias[col] : 0.f;
#pragma unroll
        for (int mi = 0; mi < 4; mi++) {
            const int row0 = (mt0 + mi) * 16 + quad * 4;
#pragma unroll
            for (int r = 0; r < 4; r++) {
                float v = acc[mi][ni][r];
                if constexpr (EPI == 0) {
                    float sgm = 1.f / (1.f + __expf(-(v + bb)));
                    obf[(size_t)(row0 + r) * ldo + col] = f2b(sgm);
                } else {
                    if (col < 1000) of32[(size_t)(row0 + r) * ldo + col] = v;
                }
            }
        }
    }
}

// ---------- host ----------
extern "C" void kernel_launch(void* const* d_in, const int* in_sizes, int n_in,
                              void* d_out, int out_size, void* d_ws, size_t ws_size,
                              hipStream_t stream) {
    const float* x   = (const float*)d_in[0];   // 8192x2048
    const float* W   = (const float*)d_in[1];   // 2048x1023
    const float* b   = (const float*)d_in[2];   // 1023
    const float* ldd = (const float*)d_in[3];   // 1024x1000
    float* out = (float*)d_out;                 // 8192x1000

    char* ws = (char*)d_ws;
    unsigned short* A2x = (unsigned short*)(ws);              // 33,554,432 B (swizzled x bf16)
    unsigned short* A2p = (unsigned short*)(ws);              // overlay: pp output (A2x dead by then)
    unsigned short* B2w = (unsigned short*)(ws + 33554432);   // 4,194,304 B (swizzled W^T)
    unsigned short* dec = (unsigned short*)(ws + 37748736);   // 16,777,216 B (row-major decisions)
    unsigned short* B2p = (unsigned short*)(ws + 54525952);   // 2,097,152 B (swizzled P^T)

    // prep: x-swizzle | W-transpose-swizzle | softmax->swizzle (independent)
    prep_kernel<<<5120, 256, 0, stream>>>(x, A2x, W, B2w, ldd, B2p);
    // decisions = sigmoid(x@W + b), row-major bf16 (cols padded to 1024)
    gemm_frag<0><<<512, 128, 0, stream>>>(A2x, B2w, b, dec, nullptr, 256, 1024);
    // pp (reference-literal order), 8 rows/block, writes swizzled A2p
    pp_kernel<<<1024, 256, 0, stream>>>(dec, A2p);
    // out = pp @ P
    gemm_frag<1><<<512, 128, 0, stream>>>(A2p, B2p, nullptr, nullptr, out, 128, 1000);
}